// Round 1
// baseline (4892.845 us; speedup 1.0000x reference)
//
#include <hip/hip_runtime.h>

// Soft-DTW forward, T=4096, D_FEAT=16, gamma=1.0, output = scalar R[T,T].
//
// Exp-domain DP: S = exp(-R), S[i,j] = E[i,j]*(S_up + S_diag + S_left),
// E = exp(-d). S carried as (mantissa in [0.5,1), int32 exponent).
// 64 blocks x 64 lanes; band w = rows [64w, 64w+64); lane = row; skewed
// wavefront (lane l computes column j = s - l at step s). Bottom-row handoff
// between bands via sentinel-initialized u64 entries + relaxed agent atomics.

constexpr int   kN         = 4096;            // T
constexpr int   kD         = 16;              // D_FEAT
constexpr int   kLanes     = 64;
constexpr int   kBands     = kN / kLanes;     // 64
constexpr int   kRowStride = kN + 8;          // u64 entries per handoff row
constexpr int   kPD        = 4;               // consumer prefetch depth (steps)
constexpr int   kSMax      = kN + kLanes;     // 4160 steps, multiple of kPD
constexpr unsigned long long kSent = 0xFFFFFFFFFFFFFFFFull;
constexpr int   kEZero     = -(1 << 30);      // exponent representing S == 0

// ws layout: [rowbuf: kBands*kRowStride u64][b2tab: kN float] ~= 2.02 MiB

__global__ __launch_bounds__(256) void sdtw_init(const float* __restrict__ B,
                                                 unsigned long long* __restrict__ rowbuf,
                                                 float* __restrict__ b2tab) {
  const int idx = blockIdx.x * blockDim.x + threadIdx.x;
  const int total = kBands * kRowStride;
  if (idx < total) {
    __hip_atomic_store(rowbuf + idx, kSent, __ATOMIC_RELAXED, __HIP_MEMORY_SCOPE_AGENT);
  }
  if (idx < kN) {
    const float4* bp = (const float4*)(B + (size_t)idx * kD);
    const float4 b0 = bp[0], b1 = bp[1], b2 = bp[2], b3 = bp[3];
    b2tab[idx] = b0.x*b0.x + b0.y*b0.y + b0.z*b0.z + b0.w*b0.w
               + b1.x*b1.x + b1.y*b1.y + b1.z*b1.z + b1.w*b1.w
               + b2.x*b2.x + b2.y*b2.y + b2.z*b2.z + b2.w*b2.w
               + b3.x*b3.x + b3.y*b3.y + b3.z*b3.z + b3.w*b3.w;
  }
}

__global__ __launch_bounds__(kLanes) void sdtw_dp(const float* __restrict__ A,
                                                  const float* __restrict__ B,
                                                  const float* __restrict__ b2tab,
                                                  unsigned long long* __restrict__ rowbuf,
                                                  float* __restrict__ out) {
  const int w = blockIdx.x;
  const int l = threadIdx.x;

  // This lane's A row (DP row i = 64w + l + 1), kept in registers.
  const float4* ap = (const float4*)(A + (size_t)(w * kLanes + l) * kD);
  const float4 A0 = ap[0], A1 = ap[1], A2v = ap[2], A3 = ap[3];
  const float a2s = A0.x*A0.x + A0.y*A0.y + A0.z*A0.z + A0.w*A0.w
                  + A1.x*A1.x + A1.y*A1.y + A1.z*A1.z + A1.w*A1.w
                  + A2v.x*A2v.x + A2v.y*A2v.y + A2v.z*A2v.z + A2v.w*A2v.w
                  + A3.x*A3.x + A3.y*A3.y + A3.z*A3.z + A3.w*A3.w;

  unsigned long long* rowme = rowbuf + (size_t)w * kRowStride;
  unsigned long long* rowpr = rowbuf + (size_t)(w > 0 ? w - 1 : 0) * kRowStride;

  // State: left value S[i, j-1] and diag carry S[i-1, j-1], extended precision.
  float pm = 0.0f; int pe = kEZero;             // S[i, 0] = 0 (left boundary)
  float dm = 0.0f; int de = kEZero;             // S[i-1, 0] = 0
  if (w == 0 && l == 0) { dm = 0.5f; de = 1; }  // S[0,0] = 1 (R[0,0] = 0)

  const bool cons = (w > 0) && (l == 0);        // consumer lane of this band
  unsigned long long cur[kPD];
#pragma unroll
  for (int q = 0; q < kPD; ++q) {
    cur[q] = kSent;
    if (cons) {
      const int j = 1 + q;
      if (j <= kN) cur[q] = __hip_atomic_load(rowpr + j, __ATOMIC_RELAXED, __HIP_MEMORY_SCOPE_AGENT);
    }
  }

  for (int g = 0; g < kSMax; g += kPD) {
    // Prefetch the next group's handoff entries (4-step latency slack).
    unsigned long long nxt[kPD];
#pragma unroll
    for (int q = 0; q < kPD; ++q) {
      nxt[q] = kSent;
      if (cons) {
        const int j = g + kPD + 1 + q;
        if (j <= kN) nxt[q] = __hip_atomic_load(rowpr + j, __ATOMIC_RELAXED, __HIP_MEMORY_SCOPE_AGENT);
      }
    }
#pragma unroll
    for (int q = 0; q < kPD; ++q) {
      const int s = g + q + 1;
      const int j = s - l;                     // 1-based column this lane computes
      const bool valid = (j >= 1) && (j <= kN);

      // up = S[i-1, j]: neighbor lane's previous-step value.
      float up_m = __shfl_up(pm, 1);
      int   up_e = __shfl_up(pe, 1);
      if (l == 0) {
        if (w == 0) {                          // padded row 0: S[0, j>=1] = 0
          up_m = 0.0f; up_e = kEZero;
        } else {                               // previous band's bottom row
          unsigned long long v = cur[q];
          if (j <= kN) {
            while (v == kSent)
              v = __hip_atomic_load(rowpr + j, __ATOMIC_RELAXED, __HIP_MEMORY_SCOPE_AGENT);
          }
          up_m = __uint_as_float((unsigned)v);
          up_e = (int)(unsigned)(v >> 32);
        }
      }

      // d(i,j) = ||a||^2 + ||b||^2 - 2 a.b  (on-the-fly; clamped addr for dead lanes)
      const int jb = min(max(j - 1, 0), kN - 1);
      const float4* bp = (const float4*)(B + (size_t)jb * kD);
      const float4 Bv0 = bp[0], Bv1 = bp[1], Bv2 = bp[2], Bv3 = bp[3];
      const float dot = A0.x*Bv0.x + A0.y*Bv0.y + A0.z*Bv0.z + A0.w*Bv0.w
                      + A1.x*Bv1.x + A1.y*Bv1.y + A1.z*Bv1.z + A1.w*Bv1.w
                      + A2v.x*Bv2.x + A2v.y*Bv2.y + A2v.z*Bv2.z + A2v.w*Bv2.w
                      + A3.x*Bv3.x + A3.y*Bv3.y + A3.z*Bv3.z + A3.w*Bv3.w;
      const float dq  = fmaf(-2.0f, dot, a2s + b2tab[jb]);
      const float t   = dq * (-1.4426950408889634f);   // -d/ln2 (gamma = 1)
      const float flr = floorf(t);
      float Em = exp2f(t - flr);                        // in [1,2)
      const int Ee = (int)flr;
      if (!valid) Em = 0.0f;                            // boundary: S -> 0

      // Extended-precision sum of up, diag, left (align to max exponent).
      const int em = max(max(up_e, de), pe);
      const float ssum = ldexpf(up_m, up_e - em)
                       + ldexpf(dm,   de   - em)
                       + ldexpf(pm,   pe   - em);
      const float mnew = ssum * Em;                     // in [0.5, 6) or 0

      // Renormalize to [0.5, 1) via exponent-bit extraction (no denormals possible).
      const unsigned mb = __float_as_uint(mnew);
      const int   fe = (int)(mb >> 23) - 126;
      const float fm = __uint_as_float((mb & 0x007FFFFFu) | 0x3F000000u);
      const bool  nz = (mnew != 0.0f);

      dm = up_m; de = up_e;                             // this up = next step's diag
      pm = nz ? fm : 0.0f;
      pe = nz ? (em + Ee + fe) : kEZero;

      // Bottom row of the band: publish for the next band.
      if (l == kLanes - 1 && valid) {
        const unsigned long long pk =
            ((unsigned long long)(unsigned)pe << 32) | (unsigned long long)__float_as_uint(pm);
        __hip_atomic_store(rowme + j, pk, __ATOMIC_RELAXED, __HIP_MEMORY_SCOPE_AGENT);
        if (w == kBands - 1 && j == kN) {
          // R[T,T] = -ln(S) = -(e + log2(m)) * ln2
          out[0] = -((float)pe + log2f(pm)) * 0.6931471805599453f;
        }
      }
    }
#pragma unroll
    for (int q = 0; q < kPD; ++q) cur[q] = nxt[q];
  }
}

extern "C" void kernel_launch(void* const* d_in, const int* in_sizes, int n_in,
                              void* d_out, int out_size, void* d_ws, size_t ws_size,
                              hipStream_t stream) {
  const float* A = (const float*)d_in[0];
  const float* B = (const float*)d_in[1];
  float* out = (float*)d_out;

  unsigned long long* rowbuf = (unsigned long long*)d_ws;
  float* b2tab = (float*)((char*)d_ws + (size_t)kBands * kRowStride * sizeof(unsigned long long));
  // ws needed: 64*4104*8 + 4096*4 = 2,117,632 bytes (~2.02 MiB)

  const int total = kBands * kRowStride;
  sdtw_init<<<(total + 255) / 256, 256, 0, stream>>>(B, rowbuf, b2tab);
  sdtw_dp<<<kBands, kLanes, 0, stream>>>(A, B, b2tab, rowbuf, out);
}

// Round 2
// 2163.852 us; speedup vs baseline: 2.2612x; 2.2612x over previous
//
#include <hip/hip_runtime.h>
#include <hip/hip_fp16.h>

typedef unsigned long long ull;

// Soft-DTW forward, T=4096, D=16, gamma=1: exp-domain DP, S=exp(-R) carried as
// (mantissa [0.5,1), int32 exponent). 32 blocks x 64 lanes, 2 rows/lane.
// Lane l, step s computes rows {128w+2l, +1} at column j=s-l.
// Row-to-row handoff inside wave: DPP wave_shr1 (VALU, no LDS latency).
// Band-to-band handoff: sentinel u64 ring + relaxed agent atomics, prefetch 8.
// E=exp(-d) precomputed as fp16 t=-d*log2e in a skewed coalesced table.

constexpr int kN     = 4096;
constexpr int kLanes = 64;
constexpr int kR     = 2;
constexpr int kBH    = kLanes * kR;          // 128 rows per band
constexpr int kBands = kN / kBH;             // 32
constexpr int kSMax  = kN + kLanes;          // 4160 local steps (mult of 8)
constexpr int kRS    = kN + 8;               // rowbuf stride (u64 entries)
constexpr int kG     = 8;                    // group / prefetch depth
constexpr ull kSent  = ~0ull;
constexpr int kEZ    = -(1 << 30);           // exponent code for S == 0
constexpr int kRowEntries = (kBands - 1) * kRS;
constexpr int kPreTot = kBands * kSMax * kLanes;
constexpr int kEtEnt  = kBands * (kSMax + 1) * kLanes;   // u32 entries

__device__ __forceinline__ int dppShr1(int v) {
  // wave_shr1: lane l <- lane l-1; lane 0 keeps old (=0), overwritten anyway.
  return __builtin_amdgcn_update_dpp(0, v, 0x138, 0xF, 0xF, false);
}

__device__ __forceinline__ float d4(float4 a, float4 b) {
  return a.x * b.x + a.y * b.y + a.z * b.z + a.w * b.w;
}

template <bool PRE>
__global__ __launch_bounds__(256) void sdtw_prep(const float* __restrict__ A,
                                                 const float* __restrict__ B,
                                                 unsigned* __restrict__ Et,
                                                 ull* __restrict__ rowbuf) {
  const int t = blockIdx.x * 256 + threadIdx.x;
  if (t < kRowEntries)
    __hip_atomic_store(rowbuf + t, kSent, __ATOMIC_RELAXED, __HIP_MEMORY_SCOPE_AGENT);
  if (!PRE) return;
  if (t >= kPreTot) return;
  const int w   = t / (kSMax * kLanes);
  const int rem = t - w * (kSMax * kLanes);
  const int s   = (rem >> 6) + 1;
  const int l   = rem & 63;
  const int j   = s - l;
  if (j < 1 || j > kN) return;                 // unwritten entries masked in DP
  const float4* Ap = (const float4*)(A + (size_t)(kBH * w + kR * l) * 16);
  const float4* Bp = (const float4*)(B + (size_t)(j - 1) * 16);
  const float4 b0 = Bp[0], b1 = Bp[1], b2v = Bp[2], b3 = Bp[3];
  const float4 x0 = Ap[0], x1 = Ap[1], x2 = Ap[2], x3 = Ap[3];   // row 2l
  const float4 y0 = Ap[4], y1 = Ap[5], y2 = Ap[6], y3 = Ap[7];   // row 2l+1
  const float bb  = d4(b0,b0) + d4(b1,b1) + d4(b2v,b2v) + d4(b3,b3);
  const float aa0 = d4(x0,x0) + d4(x1,x1) + d4(x2,x2) + d4(x3,x3);
  const float aa1 = d4(y0,y0) + d4(y1,y1) + d4(y2,y2) + d4(y3,y3);
  const float dt0 = d4(x0,b0) + d4(x1,b1) + d4(x2,b2v) + d4(x3,b3);
  const float dt1 = d4(y0,b0) + d4(y1,b1) + d4(y2,b2v) + d4(y3,b3);
  const float t0 = fmaf(-2.0f, dt0, aa0 + bb) * -1.4426950408889634f;
  const float t1 = fmaf(-2.0f, dt1, aa1 + bb) * -1.4426950408889634f;
  const unsigned pk = ((unsigned)__half_as_ushort(__float2half(t1)) << 16)
                    | (unsigned)__half_as_ushort(__float2half(t0));
  Et[(((size_t)w * (kSMax + 1) + s) << 6) + l] = pk;
}

template <bool PRE>
__global__ __launch_bounds__(kLanes) void sdtw_dp(const float* __restrict__ A,
                                                  const float* __restrict__ B,
                                                  const unsigned* __restrict__ Et,
                                                  ull* __restrict__ rowbuf,
                                                  float* __restrict__ out) {
  const int w = blockIdx.x;
  const int l = threadIdx.x;
  ull* rowme = rowbuf + (size_t)w * kRS;
  ull* rowpr = rowbuf + (size_t)(w > 0 ? w - 1 : 0) * kRS;

  // Per-row state: value at previous column (mant, exp). Col 0 boundary = 0.
  float pm0 = 0.f, pm1 = 0.f, dm = 0.f;
  int   pe0 = kEZ, pe1 = kEZ, de = kEZ;
  if (w == 0 && l == 0) { dm = 0.5f; de = 1; }   // S[0,0] = 1

  float4 x0, x1, x2, x3, y0, y1, y2, y3;
  float aa0 = 0.f, aa1 = 0.f;
  if (!PRE) {
    const float4* Ap = (const float4*)(A + (size_t)(kBH * w + kR * l) * 16);
    x0 = Ap[0]; x1 = Ap[1]; x2 = Ap[2]; x3 = Ap[3];
    y0 = Ap[4]; y1 = Ap[5]; y2 = Ap[6]; y3 = Ap[7];
    aa0 = d4(x0,x0) + d4(x1,x1) + d4(x2,x2) + d4(x3,x3);
    aa1 = d4(y0,y0) + d4(y1,y1) + d4(y2,y2) + d4(y3,y3);
  }

  const bool cons = (w > 0) && (l == 0);
  ull curP[kG];
  unsigned curE[kG];
#pragma unroll
  for (int q = 0; q < kG; ++q) {
    curP[q] = kSent;
    if (cons)
      curP[q] = __hip_atomic_load(rowpr + 1 + q, __ATOMIC_RELAXED, __HIP_MEMORY_SCOPE_AGENT);
    if (PRE)
      curE[q] = Et[(((size_t)w * (kSMax + 1) + (1 + q)) << 6) + l];
  }

  for (int g = 0; g < kSMax; g += kG) {
    ull nxtP[kG];
    unsigned nxtE[kG];
#pragma unroll
    for (int q = 0; q < kG; ++q) {
      nxtP[q] = kSent;
      const int j2 = g + kG + 1 + q;
      if (cons && j2 <= kN)
        nxtP[q] = __hip_atomic_load(rowpr + j2, __ATOMIC_RELAXED, __HIP_MEMORY_SCOPE_AGENT);
      if (PRE) {
        int s2 = g + kG + 1 + q;
        if (s2 > kSMax) s2 = kSMax;
        nxtE[q] = Et[(((size_t)w * (kSMax + 1) + s2) << 6) + l];
      }
    }
#pragma unroll
    for (int q = 0; q < kG; ++q) {
      const int s = g + q + 1;
      const int j = s - l;
      const bool jv = (j >= 1) && (j <= kN);

      // up = S[row-1, j]: previous step's bottom-row value of lane l-1.
      float um = __int_as_float(dppShr1(__float_as_int(pm1)));
      int   ue = dppShr1(pe1);
      if (w == 0) {
        if (l == 0) { um = 0.f; ue = kEZ; }          // padded row 0
      } else if (l == 0) {
        ull v = curP[q];
        if (j <= kN) {
          while (v == kSent)
            v = __hip_atomic_load(rowpr + j, __ATOMIC_RELAXED, __HIP_MEMORY_SCOPE_AGENT);
        }
        um = __uint_as_float((unsigned)v);
        ue = (int)(unsigned)(v >> 32);
      }

      float Em0, Em1;
      int Ee0, Ee1;
      if (PRE) {
        const unsigned ex = curE[q];
        const float t0 = __half2float(__ushort_as_half((unsigned short)(ex & 0xFFFFu)));
        const float t1 = __half2float(__ushort_as_half((unsigned short)(ex >> 16)));
        const float f0 = floorf(t0), f1 = floorf(t1);
        Em0 = exp2f(t0 - f0); Ee0 = (int)f0;
        Em1 = exp2f(t1 - f1); Ee1 = (int)f1;
      } else {
        const int jb = min(max(j - 1, 0), kN - 1);
        const float4* Bp = (const float4*)(B + (size_t)jb * 16);
        const float4 b0 = Bp[0], b1 = Bp[1], b2v = Bp[2], b3 = Bp[3];
        const float bb  = d4(b0,b0) + d4(b1,b1) + d4(b2v,b2v) + d4(b3,b3);
        const float dt0 = d4(x0,b0) + d4(x1,b1) + d4(x2,b2v) + d4(x3,b3);
        const float dt1 = d4(y0,b0) + d4(y1,b1) + d4(y2,b2v) + d4(y3,b3);
        const float t0 = fmaf(-2.0f, dt0, aa0 + bb) * -1.4426950408889634f;
        const float t1 = fmaf(-2.0f, dt1, aa1 + bb) * -1.4426950408889634f;
        const float f0 = floorf(t0), f1 = floorf(t1);
        Em0 = exp2f(t0 - f0); Ee0 = (int)f0;
        Em1 = exp2f(t1 - f1); Ee1 = (int)f1;
      }
      if (!jv) { Em0 = 0.f; Em1 = 0.f; }

      // cell 0 (row 2l): up(um,ue) diag(dm,de) left(pm0,pe0)
      {
        const int em = max(max(ue, de), pe0);
        const float ss = ldexpf(um, ue - em) + ldexpf(dm, de - em) + ldexpf(pm0, pe0 - em);
        const float mn = ss * Em0;                    // in [0.5,6) or 0 (or junk*0=NaN on dead lanes)
        const unsigned mb = __float_as_uint(mn);
        const int   fe = (int)(mb >> 23) - 126;
        const float fm = __uint_as_float((mb & 0x007FFFFFu) | 0x3F000000u);
        const bool  nz = (mn != 0.f);
        const float nm0 = nz ? fm : 0.f;
        const int   ne0 = nz ? (em + Ee0 + fe) : kEZ;

        // cell 1 (row 2l+1): up(nm0,ne0) diag(old pm0,pe0) left(pm1,pe1)
        const int em1 = max(max(ne0, pe0), pe1);
        const float ss1 = ldexpf(nm0, ne0 - em1) + ldexpf(pm0, pe0 - em1) + ldexpf(pm1, pe1 - em1);
        const float mn1 = ss1 * Em1;
        const unsigned mb1 = __float_as_uint(mn1);
        const int   fe1 = (int)(mb1 >> 23) - 126;
        const float fm1 = __uint_as_float((mb1 & 0x007FFFFFu) | 0x3F000000u);
        const bool  nz1 = (mn1 != 0.f);
        const float nm1 = nz1 ? fm1 : 0.f;
        const int   ne1 = nz1 ? (em1 + Ee1 + fe1) : kEZ;

        dm = um; de = ue;                             // diag carry for next column
        pm0 = nm0; pe0 = ne0;
        pm1 = nm1; pe1 = ne1;

        if (w < kBands - 1) {
          if (l == kLanes - 1 && jv) {
            const ull pk = ((ull)(unsigned)ne1 << 32) | (ull)__float_as_uint(nm1);
            __hip_atomic_store(rowme + j, pk, __ATOMIC_RELAXED, __HIP_MEMORY_SCOPE_AGENT);
          }
        } else if (l == kLanes - 1 && j == kN) {
          // R[T,T] = -(e + log2(m)) * ln2
          out[0] = -((float)ne1 + log2f(nm1)) * 0.6931471805599453f;
        }
      }
    }
#pragma unroll
    for (int q = 0; q < kG; ++q) {
      curP[q] = nxtP[q];
      if (PRE) curE[q] = nxtE[q];
    }
  }
}

extern "C" void kernel_launch(void* const* d_in, const int* in_sizes, int n_in,
                              void* d_out, int out_size, void* d_ws, size_t ws_size,
                              hipStream_t stream) {
  const float* A = (const float*)d_in[0];
  const float* B = (const float*)d_in[1];
  float* out = (float*)d_out;

  ull* rowbuf = (ull*)d_ws;
  unsigned* Et = (unsigned*)((char*)d_ws + sizeof(ull) * (size_t)kRowEntries);
  const size_t need = sizeof(ull) * (size_t)kRowEntries + sizeof(unsigned) * (size_t)kEtEnt;
  // need ~= 35.1 MB. Fallback (on-the-fly distances) needs only ~1 MB.

  if (ws_size >= need) {
    const int blocks = (kPreTot + 255) / 256;
    sdtw_prep<true><<<blocks, 256, 0, stream>>>(A, B, Et, rowbuf);
    sdtw_dp<true><<<kBands, kLanes, 0, stream>>>(A, B, Et, rowbuf, out);
  } else {
    const int blocks = (kRowEntries + 255) / 256;
    sdtw_prep<false><<<blocks, 256, 0, stream>>>(A, B, Et, rowbuf);
    sdtw_dp<false><<<kBands, kLanes, 0, stream>>>(A, B, Et, rowbuf, out);
  }
}

// Round 3
// 1395.123 us; speedup vs baseline: 3.5071x; 1.5510x over previous
//
#include <hip/hip_runtime.h>
#include <hip/hip_fp16.h>

// Soft-DTW forward, T=4096, D=16, gamma=1. Plain fp32 log-domain DP:
// R[i,j] = d(i,j) + softmin(R[i-1,j], R[i-1,j-1], R[i,j-1]),
// softmin(a,b,c) = m - ln(1 + e^{m-med} + e^{m-max}), m = min3. BIG=1e10
// boundaries survive fp32 exactly like the reference (exp(-1e10) -> 0).
// 32 blocks x 64 lanes, 2 rows/lane; skewed wavefront (lane l at step s
// computes column j = s - l). Intra-wave row handoff: DPP wave_shr1.
// Band handoff: u32 float ring, sentinel 0xFFFFFFFF, relaxed agent atomics,
// group-granular verify + prefetch (8 ahead). d precomputed as packed fp16
// pairs in a lane-contiguous table (2x dwordx4 per lane per group).

typedef unsigned int u32;

constexpr int kN      = 4096;
constexpr int kLanes  = 64;
constexpr int kBH     = 128;                 // rows per band (2 per lane)
constexpr int kBands  = kN / kBH;            // 32
constexpr int kSMax   = kN + kLanes;         // 4160 local steps
constexpr int kG      = 8;                   // steps per group
constexpr int kGroups = kSMax / kG;          // 520
constexpr int kRS     = kN + 8;              // rowbuf row stride (u32)
constexpr u32 kSent   = 0xFFFFFFFFu;         // NaN pattern, never produced
constexpr float kBig  = 1e10f;
constexpr int kRowTot = kBands * kRS;        // row 0 = BIG dummy for band 0
constexpr int kEtEnt  = kBands * kGroups * kLanes * kG;   // u32 entries

#if __has_builtin(__builtin_amdgcn_exp2f)
#define EXP2F(x) __builtin_amdgcn_exp2f(x)
#else
#define EXP2F(x) exp2f(x)
#endif
#if __has_builtin(__builtin_amdgcn_logf)
#define LOG2F(x) __builtin_amdgcn_logf(x)
#else
#define LOG2F(x) log2f(x)
#endif

__device__ __forceinline__ float med3f(float a, float b, float c) {
#if __has_builtin(__builtin_amdgcn_fmed3f)
  return __builtin_amdgcn_fmed3f(a, b, c);
#else
  return fmaxf(fminf(a, b), fminf(fmaxf(a, b), c));
#endif
}

__device__ __forceinline__ float dppShr1f(float v) {
  // lane l <- lane l-1; lane 0 gets 0 (overwritten by cndmask at use site)
  return __int_as_float(__builtin_amdgcn_update_dpp(0, __float_as_int(v), 0x138, 0xF, 0xF, false));
}

// softmin + d, gamma = 1
__device__ __forceinline__ float cell(float u, float g, float p, float d) {
  constexpr float c  = 1.4426950408889634f;   // log2 e
  constexpr float l2 = 0.6931471805599453f;   // ln 2
  const float m  = fminf(fminf(u, g), p);     // v_min3
  const float M  = fmaxf(fmaxf(u, g), p);     // v_max3
  const float md = med3f(u, g, p);            // v_med3
  const float mc = m * c;
  const float e1 = EXP2F(fmaf(md, -c, mc));
  const float e2 = EXP2F(fmaf(M,  -c, mc));
  const float lg = LOG2F(1.0f + e1 + e2);
  return fmaf(-l2, lg, d + m);
}

__global__ __launch_bounds__(256) void sdtw_prep(const float* __restrict__ A,
                                                 const float* __restrict__ B,
                                                 u32* __restrict__ Et,
                                                 u32* __restrict__ rowbuf) {
  const int tid = threadIdx.x;
  const int w   = blockIdx.y;                        // band
  const int fid = ((w * (int)gridDim.x + (int)blockIdx.x) << 8) + tid;
  if (fid < kRS)            rowbuf[fid] = __float_as_uint(kBig);  // band-0 dummy row
  else if (fid < kRowTot)   rowbuf[fid] = kSent;                  // handoff rows

  const int l = tid & 63;
  const int s = ((int)blockIdx.x << 2) + (tid >> 6) + 1;          // 1..kSMax
  const int j = s - l;
  if (j < 1 || j > kN) return;

  const float4* Ap = (const float4*)(A + (size_t)(kBH * w + 2 * l) * 16);
  const float4* Bp = (const float4*)(B + (size_t)(j - 1) * 16);
  const float4 b0 = Bp[0], b1 = Bp[1], b2 = Bp[2], b3 = Bp[3];
  const float4 x0 = Ap[0], x1 = Ap[1], x2 = Ap[2], x3 = Ap[3];   // row 2l
  const float4 y0 = Ap[4], y1 = Ap[5], y2 = Ap[6], y3 = Ap[7];   // row 2l+1
  auto sq = [](float4 a, float4 b) {
    const float dx = a.x - b.x, dy = a.y - b.y, dz = a.z - b.z, dw = a.w - b.w;
    return fmaf(dx, dx, fmaf(dy, dy, fmaf(dz, dz, dw * dw)));
  };
  const float d0 = sq(x0, b0) + sq(x1, b1) + sq(x2, b2) + sq(x3, b3);
  const float d1 = sq(y0, b0) + sq(y1, b1) + sq(y2, b2) + sq(y3, b3);
  const u32 pk = ((u32)__half_as_ushort(__float2half(d1)) << 16)
               |  (u32)__half_as_ushort(__float2half(d0));
  const int grp = (s - 1) >> 3, q = (s - 1) & 7;
  Et[((((size_t)w * kGroups + grp) * kLanes + l) << 3) + q] = pk;
}

template <bool MASK>
__device__ __forceinline__ void run_groups(
    int gBeg, int gEnd, int l, bool wLast,
    const uint4* __restrict__ EtLane,       // + grp*128 per group
    u32* __restrict__ rowpr, u32* __restrict__ rowme,
    float& p0, float& p1, float& dm,
    u32 (&curP)[kG], uint4& eA, uint4& eB, float* __restrict__ out) {
  const bool isL0  = (l == 0);
  const bool isL63 = (l == kLanes - 1);
  for (int grp = gBeg; grp < gEnd; ++grp) {
    // Prefetch next group's d-table entries (lane-contiguous, 2x dwordx4).
    const int gn = (grp + 1 < kGroups) ? grp + 1 : kGroups - 1;
    const uint4* np = EtLane + (size_t)gn * 128;
    const uint4 nA = np[0], nB = np[1];

    // Prefetch next group's handoff entries (lane 0), sentinel elsewhere.
    u32 nP[kG];
#pragma unroll
    for (int q = 0; q < kG; ++q) nP[q] = kSent;
    if (isL0) {
#pragma unroll
      for (int q = 0; q < kG; ++q) {
        const int j2 = (grp + 1) * kG + 1 + q;
        if (j2 <= kN)
          nP[q] = __hip_atomic_load(rowpr + j2, __ATOMIC_RELAXED, __HIP_MEMORY_SCOPE_AGENT);
      }
      // Verify current group's entries are published (rarely spins).
#pragma unroll
      for (int q = 0; q < kG; ++q) {
        const int j = grp * kG + 1 + q;
        if (j <= kN) {
          u32 v = curP[q];
          while (v == kSent)
            v = __hip_atomic_load(rowpr + j, __ATOMIC_RELAXED, __HIP_MEMORY_SCOPE_AGENT);
          curP[q] = v;
        }
      }
    }

    const u32 eArr[kG] = {eA.x, eA.y, eA.z, eA.w, eB.x, eB.y, eB.z, eB.w};
#pragma unroll
    for (int q = 0; q < kG; ++q) {
      const int s = grp * kG + q + 1;
      // up for cell0: lane l-1's p1; lane 0 injects the polled value.
      float um = dppShr1f(p1);
      um = isL0 ? __uint_as_float(curP[q]) : um;

      const u32 ex = eArr[q];
      const float d0 = __half2float(__ushort_as_half((unsigned short)(ex & 0xFFFFu)));
      const float d1 = __half2float(__ushort_as_half((unsigned short)(ex >> 16)));

      float r0 = cell(um, dm, p0, d0);
      if (MASK) {
        const int j = s - l;
        const bool jv = (j >= 1) && (j <= kN);
        r0 = jv ? r0 : kBig;
      }
      float r1 = cell(r0, p0, p1, d1);
      if (MASK) {
        const int j = s - l;
        const bool jv = (j >= 1) && (j <= kN);
        r1 = jv ? r1 : kBig;
      }
      dm = um; p0 = r0; p1 = r1;

      if (!wLast) {
        if (isL63) {
          int jc = s - (kLanes - 1);
          if (MASK) jc = min(max(jc, 0), kN + 1);   // park invalid in pad slots
          __hip_atomic_store(rowme + jc, __float_as_uint(r1),
                             __ATOMIC_RELAXED, __HIP_MEMORY_SCOPE_AGENT);
        }
      } else if (MASK) {
        if (isL63 && s == kN + kLanes - 1) out[0] = r1;   // R[4096,4096]
      }
    }
    eA = nA; eB = nB;
#pragma unroll
    for (int q = 0; q < kG; ++q) curP[q] = nP[q];
  }
}

__global__ __launch_bounds__(kLanes) void sdtw_dp(const u32* __restrict__ Et,
                                                  u32* __restrict__ rowbuf,
                                                  float* __restrict__ out) {
  const int w = blockIdx.x;
  const int l = threadIdx.x;
  const bool wLast = (w == kBands - 1);
  u32* rowpr = rowbuf + (size_t)w * kRS;          // band 0 -> BIG dummy row
  u32* rowme = rowbuf + (size_t)(w + 1) * kRS;    // unused for last band

  const uint4* EtLane = (const uint4*)Et + ((size_t)w * kGroups * kLanes + l) * 2;

  float p0 = kBig, p1 = kBig;                      // R[row, 0] left boundary
  float dm = (w == 0 && l == 0) ? 0.0f : kBig;     // R[row-1, 0]; R[0,0]=0

  uint4 eA = EtLane[0], eB = EtLane[1];
  u32 curP[kG];
#pragma unroll
  for (int q = 0; q < kG; ++q) {
    curP[q] = kSent;
    if (l == 0)
      curP[q] = __hip_atomic_load(rowpr + 1 + q, __ATOMIC_RELAXED, __HIP_MEMORY_SCOPE_AGENT);
  }

  // Masked prologue (s<=64 has j<1 lanes), steady unmasked, masked epilogue.
  run_groups<true >(0,   8,       l, wLast, EtLane, rowpr, rowme, p0, p1, dm, curP, eA, eB, out);
  run_groups<false>(8,   512,     l, wLast, EtLane, rowpr, rowme, p0, p1, dm, curP, eA, eB, out);
  run_groups<true >(512, kGroups, l, wLast, EtLane, rowpr, rowme, p0, p1, dm, curP, eA, eB, out);
}

extern "C" void kernel_launch(void* const* d_in, const int* in_sizes, int n_in,
                              void* d_out, int out_size, void* d_ws, size_t ws_size,
                              hipStream_t stream) {
  const float* A = (const float*)d_in[0];
  const float* B = (const float*)d_in[1];
  float* out = (float*)d_out;

  u32* rowbuf = (u32*)d_ws;
  u32* Et = rowbuf + kRowTot;
  // ws need: (131328 + 8519680) * 4 ~= 33.0 MiB (R2 proved >= 35.1 MB available)

  sdtw_prep<<<dim3(kSMax / 4, kBands), 256, 0, stream>>>(A, B, Et, rowbuf);
  sdtw_dp<<<kBands, kLanes, 0, stream>>>(Et, rowbuf, out);
}

// Round 4
// 1190.923 us; speedup vs baseline: 4.1084x; 1.1715x over previous
//
#include <hip/hip_runtime.h>
#include <hip/hip_fp16.h>

typedef unsigned int u32;

// Soft-DTW forward, T=4096, D=16, gamma=1. fp32 DP in log2-domain:
// R' = R*log2e; R'[i,j] = d'(i,j) + m - log2(1 + 2^(m-md) + 2^(m-M)),
// m/md/M = min/med/max of (up, diag, left). 64 blocks x 64 lanes, 1 row/lane
// (matches the intrinsic 8192-cell critical path). Skewed wavefront: lane l
// at local step s computes column j = s - l. Intra-band handoff: DPP
// wave_shr1. Band handoff: u32 ring + sentinel + relaxed agent atomics;
// all lanes load the same poll addresses (wave-broadcast, uniform verify),
// prefetch 2 groups (16 steps) deep. d' precomputed as fp16 (x log2e),
// lane-contiguous 16B per lane-group.

constexpr int   kN      = 4096;
constexpr int   kLanes  = 64;
constexpr int   kBands  = 64;
constexpr int   kSMax   = kN + kLanes;        // 4160
constexpr int   kG      = 8;
constexpr int   kGroups = kSMax / kG;         // 520
constexpr int   kRS     = 4176;               // ring stride (u32): 4160 + slack
constexpr u32   kSent   = 0xFFFFFFFFu;        // NaN pattern, never produced
constexpr float kBig    = 1e10f;
constexpr int   kRowTot = kBands * kRS;
constexpr float kLog2e  = 1.4426950408889634f;
constexpr float kLn2    = 0.6931471805599453f;

#if __has_builtin(__builtin_amdgcn_exp2f)
#define EXP2F(x) __builtin_amdgcn_exp2f(x)
#else
#define EXP2F(x) exp2f(x)
#endif
#if __has_builtin(__builtin_amdgcn_logf)
#define LOG2F(x) __builtin_amdgcn_logf(x)
#else
#define LOG2F(x) log2f(x)
#endif

__device__ __forceinline__ float med3f(float a, float b, float c) {
#if __has_builtin(__builtin_amdgcn_fmed3f)
  return __builtin_amdgcn_fmed3f(a, b, c);
#else
  return fmaxf(fminf(a, b), fminf(fmaxf(a, b), c));
#endif
}

__device__ __forceinline__ float dppShr1f(float v) {
  // lane l <- lane l-1; lane 0 gets old(=0), overwritten by cndmask at use.
  return __int_as_float(__builtin_amdgcn_update_dpp(0, __float_as_int(v), 0x138, 0xF, 0xF, false));
}

__device__ __forceinline__ u32 aload(const u32* p) {
  return __hip_atomic_load(p, __ATOMIC_RELAXED, __HIP_MEMORY_SCOPE_AGENT);
}

// R'-cell: softmin (log2 domain) + pre-scaled distance
__device__ __forceinline__ float cell2(float u, float g, float p, float dpv) {
  const float m  = fminf(fminf(u, g), p);
  const float M  = fmaxf(fmaxf(u, g), p);
  const float md = med3f(u, g, p);
  const float e1 = EXP2F(m - md);
  const float e2 = EXP2F(m - M);
  const float lg = LOG2F(1.0f + e1 + e2);
  return (dpv + m) - lg;
}

__global__ __launch_bounds__(256) void sdtw_prep(const float* __restrict__ A,
                                                 const float* __restrict__ B,
                                                 uint4* __restrict__ Et,
                                                 u32* __restrict__ rowbuf) {
  const int tid = threadIdx.x;
  const int w   = blockIdx.y;
  const int gid = ((w * (int)gridDim.x + (int)blockIdx.x) << 8) + tid;
  if (gid < kRS)          rowbuf[gid] = __float_as_uint(kBig);  // band-0 dummy row
  else if (gid < kRowTot) rowbuf[gid] = kSent;                  // handoff rows + pads

  const int l   = tid & 63;
  const int grp = (int)blockIdx.x * 4 + (tid >> 6);

  const float4* Ap = (const float4*)(A + (size_t)(w * 64 + l) * 16);
  const float4 a0 = Ap[0], a1 = Ap[1], a2 = Ap[2], a3 = Ap[3];
  auto sq = [](float4 a, float4 b) {
    const float dx = a.x - b.x, dy = a.y - b.y, dz = a.z - b.z, dw = a.w - b.w;
    return fmaf(dx, dx, fmaf(dy, dy, fmaf(dz, dz, dw * dw)));
  };
  u32 hp[4];
#pragma unroll
  for (int pr = 0; pr < 4; ++pr) {
    float dv[2];
#pragma unroll
    for (int h = 0; h < 2; ++h) {
      const int q = pr * 2 + h;
      const int s = grp * kG + q + 1;
      const int jb = min(max(s - l - 1, 0), kN - 1);
      const float4* Bp = (const float4*)(B + (size_t)jb * 16);
      dv[h] = (sq(a0, Bp[0]) + sq(a1, Bp[1]) + sq(a2, Bp[2]) + sq(a3, Bp[3])) * kLog2e;
    }
    hp[pr] = ((u32)__half_as_ushort(__float2half(dv[1])) << 16)
           |  (u32)__half_as_ushort(__float2half(dv[0]));
  }
  Et[((size_t)w * kGroups + grp) * 64 + l] = make_uint4(hp[0], hp[1], hp[2], hp[3]);
}

template <bool MASK>
__device__ __forceinline__ void run(int gBeg, int gEnd, int l, int w,
                                    const uint4* __restrict__ EtL,
                                    u32* __restrict__ rowpr, u32* __restrict__ rowme,
                                    float& p, float& dm,
                                    u32 (&c0)[kG], u32 (&c1)[kG],
                                    uint4& eA, uint4& eB, float* __restrict__ out) {
  const bool isL0  = (l == 0);
  const bool isL63 = (l == kLanes - 1);
  const bool wLast = (w == kBands - 1);
  for (int grp = gBeg; grp < gEnd; ++grp) {
    // Prefetch group grp+2: d'-table (16B) + handoff entries (wave-broadcast).
    int gn = grp + 2; if (gn > kGroups - 1) gn = kGroups - 1;
    const uint4 eC = EtL[(size_t)gn * 64];
    u32 n2[kG];
    const int pbase = (grp + 2) * kG;          // entry idx = j-1; pad-covered
#pragma unroll
    for (int q = 0; q < kG; ++q) n2[q] = aload(rowpr + pbase + q);

    // Verify current group's entries (uniform across wave; rare slow path).
    {
      const u32 mA = max(max(c0[0], c0[1]), max(c0[2], c0[3]));
      const u32 mB = max(max(c0[4], c0[5]), max(c0[6], c0[7]));
      if (max(mA, mB) == kSent) {
#pragma unroll
        for (int q = 0; q < kG; ++q) {
          const int j = grp * kG + 1 + q;
          if (!MASK || j <= kN) {
            u32 v = c0[q];
            while (v == kSent) v = aload(rowpr + grp * kG + q);
            c0[q] = v;
          }
        }
      }
    }

    const u32 ec[4] = {eA.x, eA.y, eA.z, eA.w};
#pragma unroll
    for (int q = 0; q < kG; ++q) {
      const int s = grp * kG + q + 1;
      float um = dppShr1f(p);
      um = isL0 ? __uint_as_float(c0[q]) : um;

      u32 hw = ec[q >> 1];
      if (q & 1) hw >>= 16;
      const float dpv = __half2float(__ushort_as_half((unsigned short)(hw & 0xFFFFu)));

      float r = cell2(um, dm, p, dpv);
      if (MASK) {
        const int j = s - l;
        r = (j >= 1 && j <= kN) ? r : kBig;
      }
      dm = um; p = r;

      if (!wLast) {
        if (isL63) {
          int idx = s - kLanes;                 // j-1 for lane 63
          if (MASK) {
            const int j = s - (kLanes - 1);
            idx = (j >= 1 && j <= kN) ? idx : kN;   // park invalid in pad
          }
          __hip_atomic_store(rowme + idx, __float_as_uint(r),
                             __ATOMIC_RELAXED, __HIP_MEMORY_SCOPE_AGENT);
        }
      } else if (MASK) {
        if (isL63 && s == kN + kLanes - 1) out[0] = r * kLn2;   // R[4096,4096]
      }
    }
    eA = eB; eB = eC;
#pragma unroll
    for (int q = 0; q < kG; ++q) { c0[q] = c1[q]; c1[q] = n2[q]; }
  }
}

__global__ __launch_bounds__(kLanes) void sdtw_dp(const uint4* __restrict__ Et,
                                                  u32* __restrict__ rowbuf,
                                                  float* __restrict__ out) {
  const int w = blockIdx.x;
  const int l = threadIdx.x;
  u32* rowpr = rowbuf + (size_t)w * kRS;        // band 0 -> BIG dummy row
  u32* rowme = rowbuf + (size_t)(w + 1) * kRS;  // never stored for last band
  const uint4* EtL = Et + (size_t)w * kGroups * 64 + l;

  float p  = kBig;                               // R'[row, 0] left boundary
  float dm = (w == 0 && l == 0) ? 0.0f : kBig;   // R'[row-1, 0]; R'[0,0]=0

  uint4 eA = EtL[0], eB = EtL[64];
  u32 c0[kG], c1[kG];
#pragma unroll
  for (int q = 0; q < kG; ++q) c0[q] = aload(rowpr + q);
#pragma unroll
  for (int q = 0; q < kG; ++q) c1[q] = aload(rowpr + kG + q);

  run<true >(0,   8,       l, w, EtL, rowpr, rowme, p, dm, c0, c1, eA, eB, out);
  run<false>(8,   512,     l, w, EtL, rowpr, rowme, p, dm, c0, c1, eA, eB, out);
  run<true >(512, kGroups, l, w, EtL, rowpr, rowme, p, dm, c0, c1, eA, eB, out);
}

extern "C" void kernel_launch(void* const* d_in, const int* in_sizes, int n_in,
                              void* d_out, int out_size, void* d_ws, size_t ws_size,
                              hipStream_t stream) {
  const float* A = (const float*)d_in[0];
  const float* B = (const float*)d_in[1];
  float* out = (float*)d_out;

  u32* rowbuf = (u32*)d_ws;
  uint4* Et = (uint4*)(rowbuf + kRowTot);
  // ws need: 64*4176*4 B + 64*520*64*16 B ~= 1.07 MB + 34.1 MB ~= 35.1 MB (fits, per R2)

  sdtw_prep<<<dim3(kGroups / 4, kBands), 256, 0, stream>>>(A, B, Et, rowbuf);
  sdtw_dp<<<kBands, kLanes, 0, stream>>>(Et, rowbuf, out);
}